// Round 1
// baseline (1773.666 us; speedup 1.0000x reference)
//
#include <hip/hip_runtime.h>

// convPbc as implicit GEMM:
//   C[M=131072][N=512] = A[M][K=4096] * W^T,  W is (512,4096) row-major (gemm_bt form)
//   m = (b, s=i*32+j), n = o, k = (c*16 + fi*4 + fj)
//   A[m][k] = pad-gather from x: p=i+fi, q=j+fj, v=35p+q
//             v<1024 -> x[b,c,v]; p>=32&&q>=32 -> x[b,c,(p-32)*32+(q-32)]; else 0
// bf16 MFMA 16x16x32, 128x128 block tile, 4 waves of 64x64, BK=32.

#define BM 128
#define BN 128
#define BK 32
#define LDA 40   // u16 elements; 80B row stride (16B aligned)
#define LDB 40

typedef __attribute__((ext_vector_type(8))) short short8;
typedef __attribute__((ext_vector_type(4))) float f32x4;

__device__ __forceinline__ unsigned short f2bf(float f) {
    union { float f; unsigned u; } v; v.f = f;
    unsigned r = v.u + 0x7FFF + ((v.u >> 16) & 1);  // RNE
    return (unsigned short)(r >> 16);
}

__global__ __launch_bounds__(256) void convpbc_mfma(
    const float* __restrict__ x,     // (128,256,1024)
    const float* __restrict__ W,     // (512,4096)
    const float* __restrict__ bias,  // (512)
    float* __restrict__ y)           // (128,512,1024)
{
    __shared__ __attribute__((aligned(16))) unsigned short Alds[BM * LDA];
    __shared__ __attribute__((aligned(16))) unsigned short Blds[BN * LDB];

    const int tid = threadIdx.x;
    const int bid = blockIdx.x;
    const int nt = bid & 3;     // 4 n-tiles (N=512)
    const int mt = bid >> 2;    // 1024 m-tiles
    const int batch = mt >> 3;  // 8 m-tiles per batch (1024/128)
    const int s0 = (mt & 7) * BM;

    const int lane = tid & 63;
    const int w    = tid >> 6;
    const int wm   = (w >> 1) * 64;
    const int wn   = (w & 1) * 64;
    const int lr   = lane & 15;
    const int quad = lane >> 4;

    // staging mapping: thread -> (row 0..127, k-half 0..1)
    const int sm   = tid >> 1;
    const int half = tid & 1;

    // A gather precompute (row sm of A tile)
    const int s  = s0 + sm;
    const int i0 = s >> 5;
    const int j0 = s & 31;

    // B row (row sm of B tile)
    const float* wrow = W + (long)(nt * BN + sm) * 4096;

    f32x4 acc[4][4] = {};

    for (int k0 = 0; k0 < 4096; k0 += BK) {
        // ---- stage A (gathered pad) ----
        {
            const int c = (k0 >> 4) + half;   // k0 multiple of 32, half*16 -> exact channel
            const float* xp = x + (((long)(batch * 256 + c)) << 10);
            __attribute__((aligned(16))) unsigned short tmp[16];
            #pragma unroll
            for (int t = 0; t < 16; ++t) {
                const int p = i0 + (t >> 2);
                const int q = j0 + (t & 3);
                const int v = p * 35 + q;
                const bool corner = (p >= 32) & (q >= 32);
                const bool valid  = corner | (v < 1024);
                int idx = corner ? (((p - 32) << 5) + (q - 32)) : v;
                idx = valid ? idx : 0;
                float fv = xp[idx];
                fv = valid ? fv : 0.0f;
                tmp[t] = f2bf(fv);
            }
            short8* dst = (short8*)&Alds[sm * LDA + half * 16];
            dst[0] = *(const short8*)&tmp[0];
            dst[1] = *(const short8*)&tmp[8];
        }
        // ---- stage B (contiguous fp32 -> bf16) ----
        {
            const float4* wv = (const float4*)(wrow + k0 + half * 16);
            __attribute__((aligned(16))) unsigned short tmp[16];
            #pragma unroll
            for (int t4 = 0; t4 < 4; ++t4) {
                const float4 f = wv[t4];
                tmp[t4 * 4 + 0] = f2bf(f.x);
                tmp[t4 * 4 + 1] = f2bf(f.y);
                tmp[t4 * 4 + 2] = f2bf(f.z);
                tmp[t4 * 4 + 3] = f2bf(f.w);
            }
            short8* dst = (short8*)&Blds[sm * LDB + half * 16];
            dst[0] = *(const short8*)&tmp[0];
            dst[1] = *(const short8*)&tmp[8];
        }
        __syncthreads();

        // ---- compute: 4x4 MFMAs per wave ----
        short8 af[4], bf[4];
        #pragma unroll
        for (int mi = 0; mi < 4; ++mi)
            af[mi] = *(const short8*)&Alds[(wm + mi * 16 + lr) * LDA + quad * 8];
        #pragma unroll
        for (int ni = 0; ni < 4; ++ni)
            bf[ni] = *(const short8*)&Blds[(wn + ni * 16 + lr) * LDB + quad * 8];
        #pragma unroll
        for (int mi = 0; mi < 4; ++mi)
            #pragma unroll
            for (int ni = 0; ni < 4; ++ni)
                acc[mi][ni] = __builtin_amdgcn_mfma_f32_16x16x32_bf16(
                    af[mi], bf[ni], acc[mi][ni], 0, 0, 0);
        __syncthreads();
    }

    // ---- epilogue: C/D layout col=lane&15, row=quad*4+r ----
    #pragma unroll
    for (int ni = 0; ni < 4; ++ni) {
        const int ngl = nt * BN + wn + ni * 16 + lr;
        const float bv = bias[ngl];
        float* ybase = y + (((long)(batch * 512 + ngl)) << 10) + s0;
        #pragma unroll
        for (int mi = 0; mi < 4; ++mi) {
            const int mbase = wm + mi * 16 + quad * 4;
            #pragma unroll
            for (int r = 0; r < 4; ++r)
                ybase[mbase + r] = acc[mi][ni][r] + bv;
        }
    }
}

extern "C" void kernel_launch(void* const* d_in, const int* in_sizes, int n_in,
                              void* d_out, int out_size, void* d_ws, size_t ws_size,
                              hipStream_t stream) {
    const float* x    = (const float*)d_in[0];
    const float* W    = (const float*)d_in[1];
    const float* bias = (const float*)d_in[2];
    float* y          = (float*)d_out;

    dim3 grid(4096), block(256);
    hipLaunchKernelGGL(convpbc_mfma, grid, block, 0, stream, x, W, bias, y);
}

// Round 2
// 1641.132 us; speedup vs baseline: 1.0808x; 1.0808x over previous
//
#include <hip/hip_runtime.h>

// convPbc as implicit GEMM, round 2:
//   Pre-pass 1: build helically-padded x in ws as bf16: xpad[b,c,v], v=35p+q, 1225/channel.
//   Pre-pass 2: convert W to bf16 (512x4096) in ws.
//   Main: C[M][N] = A * W^T via mfma_f32_16x16x32_bf16, 128x128 tile, 4 waves 64x64.
//     A frags: DIRECT from xpad (two contiguous 8B loads per frag - helical pad makes
//              each lane's 8 taps = 2 runs of 4 consecutive flat elements). No LDS, no cvt.
//     B frags: global_load_lds width=16 from W_bf16 into 8KB LDS tile, XOR-swizzled
//              k-segments so frag ds_read_b128 spreads 2-way over banks (free, m136).

#define BM 128
#define BN 128

typedef __attribute__((ext_vector_type(8))) short short8;
typedef __attribute__((ext_vector_type(4))) float f32x4;

struct __attribute__((packed)) u16x4 { unsigned short a, b, c, d; };  // 8B, 2B-align

__device__ __forceinline__ unsigned short f2bf(float f) {
    union { float f; unsigned u; } v; v.f = f;
    unsigned r = v.u + 0x7FFF + ((v.u >> 16) & 1);  // RNE
    return (unsigned short)(r >> 16);
}

__device__ __forceinline__ void async_b128(const void* g, void* l) {
    __builtin_amdgcn_global_load_lds(
        (const __attribute__((address_space(1))) void*)g,
        (__attribute__((address_space(3))) void*)l, 16, 0, 0);
}

// ---------------- pre-pass kernels ----------------
__global__ __launch_bounds__(256) void build_pad(const float* __restrict__ x,
                                                 unsigned short* __restrict__ xp) {
    const int v = blockIdx.x * 256 + threadIdx.x;   // 0..1279
    const int bc = blockIdx.y;                      // 0..32767
    if (v >= 1225) return;
    const int p = (v * 7490) >> 18;                 // exact v/35 for v<43690
    const int q = v - p * 35;
    const float* xb = x + (long)bc * 1024;
    float val = (v < 1024) ? xb[v] : 0.0f;
    if (p >= 32 && q >= 32) val += xb[((p - 32) << 5) + (q - 32)];
    xp[(long)bc * 1225 + v] = f2bf(val);
}

__global__ __launch_bounds__(256) void cvt_w(const float* __restrict__ W,
                                             unsigned short* __restrict__ Wb) {
    const int idx = blockIdx.x * 256 + threadIdx.x;  // 2M
    Wb[idx] = f2bf(W[idx]);
}

// ---------------- main kernel ----------------
__global__ __launch_bounds__(256) void convpbc_mfma2(
    const unsigned short* __restrict__ xpad,  // (128,256,1225) bf16
    const unsigned short* __restrict__ Wb,    // (512,4096) bf16
    const float* __restrict__ bias,
    float* __restrict__ y)
{
    __shared__ __attribute__((aligned(16))) unsigned short Blds[BN * 32];  // 8 KB

    const int tid = threadIdx.x;
    const int bid = blockIdx.x;
    const int nt = bid & 3;
    const int mt = bid >> 2;
    const int batch = mt >> 3;
    const int s0 = (mt & 7) * BM;
    const int i0 = (mt & 7) * 4;

    const int lane = tid & 63;
    const int w    = tid >> 6;
    const int wm   = (w >> 1) * 64;
    const int wn   = (w & 1) * 64;
    const int lr   = lane & 15;
    const int quad = lane >> 4;

    // ---- A direct-load setup ----
    // k = c*16 + t, t=(fi,fj). quad -> (channel parity, fi0): c = base+(quad>>1), fi0=(quad&1)*2.
    const int fi0 = (quad & 1) * 2;
    const unsigned short* ab = xpad + (long)(batch * 256 + (quad >> 1)) * 1225;
    int aoff[4];
    #pragma unroll
    for (int mi = 0; mi < 4; ++mi) {
        const int i_mi = i0 + (wm >> 5) + (mi >> 1) + fi0;  // p for the fi0 row
        const int j_mi = (mi & 1) * 16 + lr;
        aoff[mi] = i_mi * 35 + j_mi;                         // flat helical offset
    }

    // ---- B staging setup (global_load_lds, XOR-swizzled k-segments) ----
    // wave w stages rows w*32..w*32+31 (two 1024B DMAs). lane -> (row=lane>>2, seg=lane&3);
    // LDS slot (row,seg) holds global k-chunk seg^((row>>1)&3).
    const int brow0 = w * 32 + (lane >> 2);
    const int brow1 = brow0 + 16;
    const int bseg  = lane & 3;
    const unsigned short* bg0 =
        Wb + (long)(nt * BN + brow0) * 4096 + (bseg ^ ((brow0 >> 1) & 3)) * 8;
    const unsigned short* bg1 =
        Wb + (long)(nt * BN + brow1) * 4096 + (bseg ^ ((brow1 >> 1) & 3)) * 8;
    unsigned short* blds0 = &Blds[(w * 32) * 32];        // wave-uniform bases
    unsigned short* blds1 = &Blds[(w * 32 + 16) * 32];

    // frag read addresses (u16 units), swizzle-corrected
    int bfaddr[4];
    #pragma unroll
    for (int ni = 0; ni < 4; ++ni) {
        const int row = wn + ni * 16 + lr;
        bfaddr[ni] = row * 32 + (quad ^ ((row >> 1) & 3)) * 8;
    }

    f32x4 acc[4][4] = {};

    for (int k0 = 0; k0 < 4096; k0 += 32) {
        // stage B tile for this k-chunk (rows-done barrier is at loop bottom)
        async_b128(bg0 + k0, blds0);
        async_b128(bg1 + k0, blds1);

        // A frags direct from global (two contiguous 8B runs per frag)
        short8 af[4];
        #pragma unroll
        for (int mi = 0; mi < 4; ++mi) {
            union { unsigned short h[8]; short8 f; } u;
            *(u16x4*)&u.h[0] = *(const u16x4*)(ab + aoff[mi]);        // fi0 row
            *(u16x4*)&u.h[4] = *(const u16x4*)(ab + aoff[mi] + 35);   // fi0+1 row
            af[mi] = u.f;
        }
        ab += 2450;  // advance 2 channels

        __syncthreads();  // drains vmcnt (DMA + A loads) then barrier -> B tile visible

        short8 bf[4];
        #pragma unroll
        for (int ni = 0; ni < 4; ++ni)
            bf[ni] = *(const short8*)&Blds[bfaddr[ni]];
        #pragma unroll
        for (int mi = 0; mi < 4; ++mi)
            #pragma unroll
            for (int ni = 0; ni < 4; ++ni)
                acc[mi][ni] = __builtin_amdgcn_mfma_f32_16x16x32_bf16(
                    af[mi], bf[ni], acc[mi][ni], 0, 0, 0);

        __syncthreads();  // all reads done before next iter's DMA overwrites
    }

    // ---- epilogue: C/D layout col=lane&15, row=quad*4+r ----
    #pragma unroll
    for (int ni = 0; ni < 4; ++ni) {
        const int ngl = nt * BN + wn + ni * 16 + lr;
        const float bv = bias[ngl];
        float* ybase = y + (((long)(batch * 512 + ngl)) << 10) + s0;
        #pragma unroll
        for (int mi = 0; mi < 4; ++mi) {
            const int mbase = wm + mi * 16 + quad * 4;
            #pragma unroll
            for (int r = 0; r < 4; ++r)
                ybase[mbase + r] = acc[mi][ni][r] + bv;
        }
    }
}

// ---------------- legacy fallback (round-1 kernel) ----------------
#define LDA 40
#define LDB 40
__global__ __launch_bounds__(256) void convpbc_mfma(
    const float* __restrict__ x, const float* __restrict__ W,
    const float* __restrict__ bias, float* __restrict__ y)
{
    __shared__ __attribute__((aligned(16))) unsigned short Alds[BM * LDA];
    __shared__ __attribute__((aligned(16))) unsigned short BldsL[BN * LDB];
    const int tid = threadIdx.x, bid = blockIdx.x;
    const int nt = bid & 3, mt = bid >> 2, batch = mt >> 3;
    const int s0 = (mt & 7) * BM;
    const int lane = tid & 63, w = tid >> 6;
    const int wm = (w >> 1) * 64, wn = (w & 1) * 64;
    const int lr = lane & 15, quad = lane >> 4;
    const int sm = tid >> 1, half = tid & 1;
    const int s = s0 + sm, i0 = s >> 5, j0 = s & 31;
    const float* wrow = W + (long)(nt * BN + sm) * 4096;
    f32x4 acc[4][4] = {};
    for (int k0 = 0; k0 < 4096; k0 += 32) {
        {
            const int c = (k0 >> 4) + half;
            const float* xp = x + (((long)(batch * 256 + c)) << 10);
            __attribute__((aligned(16))) unsigned short tmp[16];
            #pragma unroll
            for (int t = 0; t < 16; ++t) {
                const int p = i0 + (t >> 2), q = j0 + (t & 3);
                const int v = p * 35 + q;
                const bool corner = (p >= 32) & (q >= 32);
                const bool valid = corner | (v < 1024);
                int idx = corner ? (((p - 32) << 5) + (q - 32)) : v;
                idx = valid ? idx : 0;
                float fv = xp[idx];
                fv = valid ? fv : 0.0f;
                tmp[t] = f2bf(fv);
            }
            short8* dst = (short8*)&Alds[sm * LDA + half * 16];
            dst[0] = *(const short8*)&tmp[0];
            dst[1] = *(const short8*)&tmp[8];
        }
        {
            const float4* wv = (const float4*)(wrow + k0 + half * 16);
            __attribute__((aligned(16))) unsigned short tmp[16];
            #pragma unroll
            for (int t4 = 0; t4 < 4; ++t4) {
                const float4 f = wv[t4];
                tmp[t4 * 4 + 0] = f2bf(f.x); tmp[t4 * 4 + 1] = f2bf(f.y);
                tmp[t4 * 4 + 2] = f2bf(f.z); tmp[t4 * 4 + 3] = f2bf(f.w);
            }
            short8* dst = (short8*)&BldsL[sm * LDB + half * 16];
            dst[0] = *(const short8*)&tmp[0];
            dst[1] = *(const short8*)&tmp[8];
        }
        __syncthreads();
        short8 af[4], bf[4];
        #pragma unroll
        for (int mi = 0; mi < 4; ++mi)
            af[mi] = *(const short8*)&Alds[(wm + mi * 16 + lr) * LDA + quad * 8];
        #pragma unroll
        for (int ni = 0; ni < 4; ++ni)
            bf[ni] = *(const short8*)&BldsL[(wn + ni * 16 + lr) * LDB + quad * 8];
        #pragma unroll
        for (int mi = 0; mi < 4; ++mi)
            #pragma unroll
            for (int ni = 0; ni < 4; ++ni)
                acc[mi][ni] = __builtin_amdgcn_mfma_f32_16x16x32_bf16(
                    af[mi], bf[ni], acc[mi][ni], 0, 0, 0);
        __syncthreads();
    }
    #pragma unroll
    for (int ni = 0; ni < 4; ++ni) {
        const int ngl = nt * BN + wn + ni * 16 + lr;
        const float bv = bias[ngl];
        float* ybase = y + (((long)(batch * 512 + ngl)) << 10) + s0;
        #pragma unroll
        for (int mi = 0; mi < 4; ++mi) {
            const int mbase = wm + mi * 16 + quad * 4;
            #pragma unroll
            for (int r = 0; r < 4; ++r)
                ybase[mbase + r] = acc[mi][ni][r] + bv;
        }
    }
}

extern "C" void kernel_launch(void* const* d_in, const int* in_sizes, int n_in,
                              void* d_out, int out_size, void* d_ws, size_t ws_size,
                              hipStream_t stream) {
    const float* x    = (const float*)d_in[0];
    const float* W    = (const float*)d_in[1];
    const float* bias = (const float*)d_in[2];
    float* y          = (float*)d_out;

    const size_t XPAD_ELEMS = 128L * 256 * 1225;        // 40,140,800
    const size_t W_ELEMS    = 512L * 4096;              // 2,097,152
    const size_t NEED = (XPAD_ELEMS + W_ELEMS) * 2;     // ~84.5 MB

    if (ws_size >= NEED) {
        unsigned short* xpad = (unsigned short*)d_ws;
        unsigned short* Wb   = xpad + XPAD_ELEMS;
        hipLaunchKernelGGL(build_pad, dim3(5, 128 * 256), dim3(256), 0, stream, x, xpad);
        hipLaunchKernelGGL(cvt_w, dim3(8192), dim3(256), 0, stream, W, Wb);
        hipLaunchKernelGGL(convpbc_mfma2, dim3(4096), dim3(256), 0, stream,
                           xpad, Wb, bias, y);
    } else {
        hipLaunchKernelGGL(convpbc_mfma, dim3(4096), dim3(256), 0, stream, x, W, bias, y);
    }
}